// Round 7
// baseline (253.523 us; speedup 1.0000x reference)
//
#include <hip/hip_runtime.h>
#include <math.h>

#define N_V   8192
#define N_E   4096
#define V_HID 128
#define H0_   64
#define CAP   96      // row nz capacity  (mean 41, sigma 6.4)
#define CAPC  144     // col nz capacity  (mean 82, sigma 9.0)
#define BN_EPS 1e-5f
#define NPROJ (N_V / 16)   // 512 proj blocks

typedef unsigned int   u32;
typedef unsigned long long u64;

// ============================================================================
// kA: merged proj + scan. PROJ blocks come FIRST (0..511) so they are
// dispatched and co-resident with the BW-bound scan from t=0 — their VALU/L2
// work hides under the scan's HBM streaming instead of running as an exposed
// tail (block dispatch is in-order as resources free).
// Scan blocks are 512..2559, one wave per H row.
// colcnt/bnp pre-zeroed by hipMemsetAsync before this kernel.
// ============================================================================
__global__ __launch_bounds__(256) void kA_scan_proj(
    const float* __restrict__ Hf, const float* __restrict__ X,
    const float* __restrict__ th1, const float* __restrict__ Dv,
    float* __restrict__ P,
    u32* __restrict__ nzlist, u32* __restrict__ nzcnt,
    u32* __restrict__ colcnt, u32* __restrict__ colentry)
{
    __shared__ __align__(16) char sm[8192];
    const int tid  = threadIdx.x;
    const int bid  = blockIdx.x;
    const int lane = tid & 63;
    const int wv   = tid >> 6;

    if (bid >= NPROJ) {
        // ---- scan branch (blocks 512..2559): identical math to proven k2a ----
        u32* rowbuf = (u32*)sm;             // [4][CAP]
        int n = (bid - NPROJ) * 4 + wv;
        const uint4* hrow4 = (const uint4*)(Hf + (size_t)n * N_E);
        u64 ltmask = (lane == 63) ? 0x7FFFFFFFFFFFFFFFull : ((1ull << lane) - 1ull);
        uint4 q[16];
#pragma unroll
        for (int m = 0; m < 16; ++m)        // whole 16 KB row in flight
            q[m] = hrow4[m * 64 + lane];
        u32 cnt = 0;
#pragma unroll
        for (int m = 0; m < 16; ++m) {
            int ebase = (m * 64 + lane) * 4;
            u32 words[4] = { q[m].x, q[m].y, q[m].z, q[m].w };
#pragma unroll
            for (int j = 0; j < 4; ++j) {
                bool has = (words[j] & 0x7FFFFFFFu) != 0u;
                u64 bal = __ballot(has);
                if (bal) {                  // wave-uniform skip
                    if (has) {
                        u32 slot = cnt + (u32)__popcll(bal & ltmask);
                        if (slot < CAP) rowbuf[wv * CAP + slot] = (u32)(ebase + j);
                    }
                    cnt += (u32)__popcll(bal);
                }
            }
        }
        if (cnt > CAP) cnt = CAP;
        if (lane == 0) nzcnt[n] = cnt;
        for (u32 i = lane; i < cnt; i += 64) {
            u32 e = rowbuf[wv * CAP + i];
            nzlist[(size_t)n * CAP + i] = e;
            u32 cs = atomicAdd(&colcnt[e], 1u);
            if (cs < CAPC) colentry[(size_t)e * CAPC + cs] = (u32)n;
        }
    } else {
        // ---- proj branch (blocks 0..511): 16 rows per block, th1 from L2 ----
        float (*Xs)[V_HID] = (float (*)[V_HID])sm;   // 16 x 128 f32 = 8 KB
        int n0 = bid * 16;
        const float4* xr = (const float4*)(X + (size_t)n0 * V_HID);
        for (int i = tid; i < 512; i += 256) {
            float4 f = xr[i];
            int b = 4 * i;
            Xs[b >> 7][(b & 127) + 0] = f.x;
            Xs[b >> 7][(b & 127) + 1] = f.y;
            Xs[b >> 7][(b & 127) + 2] = f.z;
            Xs[b >> 7][(b & 127) + 3] = f.w;
        }
        __syncthreads();
        int r0 = wv * 4;
        float a0 = 0.f, a1 = 0.f, a2 = 0.f, a3 = 0.f;
#pragma unroll 8
        for (int k = 0; k < V_HID; ++k) {
            float tt = th1[k * H0_ + lane];   // coalesced 256B, L2-hot
            a0 += tt * Xs[r0 + 0][k];
            a1 += tt * Xs[r0 + 1][k];
            a2 += tt * Xs[r0 + 2][k];
            a3 += tt * Xs[r0 + 3][k];
        }
        P[(size_t)(n0 + r0 + 0) * H0_ + lane] = Dv[n0 + r0 + 0] * a0;
        P[(size_t)(n0 + r0 + 1) * H0_ + lane] = Dv[n0 + r0 + 1] * a1;
        P[(size_t)(n0 + r0 + 2) * H0_ + lane] = Dv[n0 + r0 + 2] * a2;
        P[(size_t)(n0 + r0 + 3) * H0_ + lane] = Dv[n0 + r0 + 3] * a3;
    }
}

// K2b: Mp[e,:] = W[e]*De[e] * sum_colnz P[n,:]   (gather, 8 loads in flight)
__global__ __launch_bounds__(256) void k2b_gather(const u32* __restrict__ colcnt, const u32* __restrict__ colentry,
                                                  const float* __restrict__ P, const float* __restrict__ W,
                                                  const float* __restrict__ De, float* __restrict__ Mp) {
    int lane = threadIdx.x & 63;
    int e = blockIdx.x * 4 + (threadIdx.x >> 6);
    u32 cw = colcnt[e];
    int cnt = cw < CAPC ? (int)cw : CAPC;
    const u32* ce = colentry + (size_t)e * CAPC;
    float acc0 = 0.f, acc1 = 0.f;
    int i = 0;
    for (; i + 8 <= cnt; i += 8) {
        uint4 a = *((const uint4*)(ce + i));
        uint4 b = *((const uint4*)(ce + i + 4));
        float p0 = P[(a.x & (N_V - 1)) * H0_ + lane];
        float p1 = P[(a.y & (N_V - 1)) * H0_ + lane];
        float p2 = P[(a.z & (N_V - 1)) * H0_ + lane];
        float p3 = P[(a.w & (N_V - 1)) * H0_ + lane];
        float p4 = P[(b.x & (N_V - 1)) * H0_ + lane];
        float p5 = P[(b.y & (N_V - 1)) * H0_ + lane];
        float p6 = P[(b.z & (N_V - 1)) * H0_ + lane];
        float p7 = P[(b.w & (N_V - 1)) * H0_ + lane];
        acc0 += (p0 + p1) + (p2 + p3);
        acc1 += (p4 + p5) + (p6 + p7);
    }
    for (; i < cnt; ++i)
        acc0 += P[(ce[i] & (N_V - 1)) * H0_ + lane];
    Mp[(size_t)e * H0_ + lane] = W[e] * De[e] * (acc0 + acc1);
}

// K3: X1[n,:] = leaky_relu(Dv[n]*sum_rownz Mp[e,:]); BN partial sums
__global__ __launch_bounds__(256) void k3_layer1(const u32* __restrict__ nzlist, const u32* __restrict__ nzcnt,
                                                 const float* __restrict__ Mp, const float* __restrict__ Dv,
                                                 float* __restrict__ X1, float* __restrict__ bnp) {
    int lane = threadIdx.x & 63;
    int wv = threadIdx.x >> 6;
    int n = blockIdx.x * 4 + wv;
    const u32* lrow = nzlist + (size_t)n * CAP;
    u32 cw = nzcnt[n];
    int cnt = cw < CAP ? (int)cw : CAP;
    float acc0 = 0.f, acc1 = 0.f;
    int i = 0;
    for (; i + 8 <= cnt; i += 8) {
        uint4 a = *((const uint4*)(lrow + i));
        uint4 b = *((const uint4*)(lrow + i + 4));
        float p0 = Mp[(a.x & (N_E - 1)) * H0_ + lane];
        float p1 = Mp[(a.y & (N_E - 1)) * H0_ + lane];
        float p2 = Mp[(a.z & (N_E - 1)) * H0_ + lane];
        float p3 = Mp[(a.w & (N_E - 1)) * H0_ + lane];
        float p4 = Mp[(b.x & (N_E - 1)) * H0_ + lane];
        float p5 = Mp[(b.y & (N_E - 1)) * H0_ + lane];
        float p6 = Mp[(b.z & (N_E - 1)) * H0_ + lane];
        float p7 = Mp[(b.w & (N_E - 1)) * H0_ + lane];
        acc0 += (p0 + p1) + (p2 + p3);
        acc1 += (p4 + p5) + (p6 + p7);
    }
    for (; i < cnt; ++i)
        acc0 += Mp[(lrow[i] & (N_E - 1)) * H0_ + lane];
    float xb = Dv[n] * (acc0 + acc1);
    float x1 = xb > 0.f ? xb : 0.01f * xb;
    X1[(size_t)n * H0_ + lane] = x1;
    __shared__ float ssum[4][H0_], ssq[4][H0_];
    ssum[wv][lane] = x1;
    ssq[wv][lane] = x1 * x1;
    __syncthreads();
    if (wv == 0) {
        float a = ssum[0][lane] + ssum[1][lane] + ssum[2][lane] + ssum[3][lane];
        float b = ssq[0][lane] + ssq[1][lane] + ssq[2][lane] + ssq[3][lane];
        float* dst = bnp + (size_t)(blockIdx.x & 7) * 128;
        atomicAdd(&dst[lane], a);
        atomicAdd(&dst[64 + lane], b);
    }
}

// K5: BN apply + theta2 dot; P2v[n] = Dv[n] * (BN(X1[n,:]).th2)
__global__ __launch_bounds__(256) void k5_bn_proj(const float* __restrict__ X1, const float* __restrict__ bnp,
                                                  const float* __restrict__ gamma, const float* __restrict__ beta,
                                                  const float* __restrict__ th2, const float* __restrict__ Dv,
                                                  float* __restrict__ P2v) {
    int lane = threadIdx.x & 63;
    int n = (int)((blockIdx.x * 256 + threadIdx.x) >> 6);
    float sum = 0.f, sq = 0.f;
#pragma unroll
    for (int p = 0; p < 8; ++p) { sum += bnp[p * 128 + lane]; sq += bnp[p * 128 + 64 + lane]; }
    float mu = sum * (1.f / N_V);
    float var = sq * (1.f / N_V) - mu * mu;
    float inv = rsqrtf(var + BN_EPS);
    float x = X1[(size_t)n * H0_ + lane];
    float xn = (x - mu) * inv * gamma[lane] + beta[lane];
    float t = xn * th2[lane];
#pragma unroll
    for (int off = 32; off > 0; off >>= 1) t += __shfl_xor(t, off);
    if (lane == 0) P2v[n] = Dv[n] * t;
}

// K6: M2p[e] = W[e]*De[e] * sum_colnz P2v[n]   (gather — proven fast)
__global__ __launch_bounds__(256) void k6_edge2(const u32* __restrict__ colcnt, const u32* __restrict__ colentry,
                                                const float* __restrict__ P2v, const float* __restrict__ W,
                                                const float* __restrict__ De, float* __restrict__ M2p) {
    int lane = threadIdx.x & 63;
    int e = blockIdx.x * 4 + (threadIdx.x >> 6);
    u32 cw = colcnt[e];
    int cnt = cw < CAPC ? (int)cw : CAPC;
    const u32* ce = colentry + (size_t)e * CAPC;
    float s = 0.f;
    for (int i = lane; i < cnt; i += 64)
        s += P2v[ce[i] & (N_V - 1)];
#pragma unroll
    for (int off = 32; off > 0; off >>= 1) s += __shfl_xor(s, off);
    if (lane == 0) M2p[e] = W[e] * De[e] * s;
}

// K7: out[n] = sigmoid(Dv[n] * sum_rownz M2p[e])   (gather — proven fast)
__global__ __launch_bounds__(256) void k7_out(const u32* __restrict__ nzlist, const u32* __restrict__ nzcnt,
                                              const float* __restrict__ M2p, const float* __restrict__ Dv,
                                              float* __restrict__ out) {
    int lane = threadIdx.x & 63;
    int n = blockIdx.x * 4 + (threadIdx.x >> 6);
    u32 cw = nzcnt[n];
    int cnt = cw < CAP ? (int)cw : CAP;
    const u32* lrow = nzlist + (size_t)n * CAP;
    float s = 0.f;
    for (int i = lane; i < cnt; i += 64)
        s += M2p[lrow[i] & (N_E - 1)];
#pragma unroll
    for (int off = 32; off > 0; off >>= 1) s += __shfl_xor(s, off);
    if (lane == 0) {
        float xb = Dv[n] * s;
        out[n] = 1.f / (1.f + expf(-xb));
    }
}

extern "C" void kernel_launch(void* const* d_in, const int* in_sizes, int n_in,
                              void* d_out, int out_size, void* d_ws, size_t ws_size,
                              hipStream_t stream) {
    const float* X   = (const float*)d_in[0];
    const float* Dv  = (const float*)d_in[1];
    const float* De  = (const float*)d_in[2];
    const float* Hf  = (const float*)d_in[3];
    const float* W   = (const float*)d_in[4];
    const float* th1 = (const float*)d_in[5];
    const float* th2 = (const float*)d_in[6];
    const float* gm  = (const float*)d_in[7];
    const float* bt  = (const float*)d_in[8];
    float* out = (float*)d_out;

    char* ws = (char*)d_ws;
    u32*   colcnt   = (u32*)  (ws + 0);         // 4096*4 = 16384
    float* bnp      = (float*)(ws + 16384);     // 1024*4 -> 20480   [memset 0..20480]
    u32*   nzcnt    = (u32*)  (ws + 20480);     // 8192*4 -> 53248
    float* M2p      = (float*)(ws + 53248);     // 4096*4 -> 69632
    float* P2v      = (float*)(ws + 69632);     // 8192*4 -> 102400
    float* P        = (float*)(ws + 131072);    // 8192*64*4 = 2 MB -> 2228224
    float* X1       = P;                        // reuse: P dead after k2b
    float* Mp       = (float*)(ws + 2228224);   // 4096*64*4 = 1 MB -> 3276800
    u32*   nzlist   = (u32*)  (ws + 3276800);   // 8192*96*4 = 3 MB -> 6422528
    u32*   colentry = (u32*)  (ws + 6422528);   // 4096*144*4 = 2.25 MB -> 8781824

    hipMemsetAsync(ws, 0, 20480, stream);       // colcnt + bnp
    kA_scan_proj<<<NPROJ + N_V / 4, 256, 0, stream>>>(Hf, X, th1, Dv, P,
                                                      nzlist, nzcnt, colcnt, colentry);
    k2b_gather<<<N_E / 4, 256, 0, stream>>>(colcnt, colentry, P, W, De, Mp);
    k3_layer1<<<N_V / 4, 256, 0, stream>>>(nzlist, nzcnt, Mp, Dv, X1, bnp);
    k5_bn_proj<<<N_V / 4, 256, 0, stream>>>(X1, bnp, gm, bt, th2, Dv, P2v);
    k6_edge2<<<N_E / 4, 256, 0, stream>>>(colcnt, colentry, P2v, W, De, M2p);
    k7_out<<<N_V / 4, 256, 0, stream>>>(nzlist, nzcnt, M2p, Dv, out);
}